// Round 9
// baseline (321.730 us; speedup 1.0000x reference)
//
#include <hip/hip_runtime.h>
#include <hip/hip_bf16.h>
#include <stdint.h>

// Problem constants
#define BB    4
#define NH    16
#define SEQ   2048
#define DH    64
#define EMB   1024
#define KD    1024
#define MROWS 8192   // BB*SEQ

typedef short  short8  __attribute__((ext_vector_type(8)));
typedef float  f32x4   __attribute__((ext_vector_type(4)));
typedef float  f32x16  __attribute__((ext_vector_type(16)));

typedef const __attribute__((address_space(1))) void* gas_t;
typedef __attribute__((address_space(3))) void*       las_t;
#define GLD16(g, l) __builtin_amdgcn_global_load_lds((gas_t)(g), (las_t)(l), 16, 0, 0)

__device__ __forceinline__ unsigned short f2bf(float f) {
    unsigned u = __float_as_uint(f);
    u += 0x7fffu + ((u >> 16) & 1u);   // RNE
    return (unsigned short)(u >> 16);
}
__device__ __forceinline__ unsigned packbf(float lo, float hi) {
    union { __hip_bfloat162 h; unsigned u; } cv;
    cv.h = __float22bfloat162_rn(make_float2(lo, hi));   // v_cvt_pk_bf16_f32
    return cv.u;
}

// ---------------------------------------------------------------------------
// Kernel 1: Wt[p][n][k] = bf16(W[p][k][n])
// ---------------------------------------------------------------------------
__global__ __launch_bounds__(256) void wt_kernel(const float* __restrict__ Wq,
                                                 const float* __restrict__ Wk,
                                                 const float* __restrict__ Wv,
                                                 unsigned short* __restrict__ Wt) {
    __shared__ float tsh[64 * 68];
    const int p = blockIdx.z;
    const float* W = (p == 0) ? Wq : (p == 1) ? Wk : Wv;
    unsigned short* dst = Wt + (size_t)p * (KD * EMB);
    const int k0 = blockIdx.x * 64, n0 = blockIdx.y * 64;
    const int t = threadIdx.x;
    {
        const int r = t >> 2, c4 = (t & 3) * 16;
        const float* g = W + (size_t)(k0 + r) * EMB + n0 + c4;
        float* row = &tsh[r * 68 + c4];
        *(float4*)(row + 0)  = *(const float4*)(g + 0);
        *(float4*)(row + 4)  = *(const float4*)(g + 4);
        *(float4*)(row + 8)  = *(const float4*)(g + 8);
        *(float4*)(row + 12) = *(const float4*)(g + 12);
    }
    __syncthreads();
    {
        const int j = t >> 2, kp = (t & 3) * 16;
        unsigned ub[8];
#pragma unroll
        for (int ii = 0; ii < 8; ++ii)
            ub[ii] = packbf(tsh[(kp + 2 * ii) * 68 + j], tsh[(kp + 2 * ii + 1) * 68 + j]);
        unsigned short* o = dst + (size_t)(n0 + j) * KD + k0 + kp;
        *(uint4*)(o + 0) = uint4{ub[0], ub[1], ub[2], ub[3]};
        *(uint4*)(o + 8) = uint4{ub[4], ub[5], ub[6], ub[7]};
    }
}

// ---------------------------------------------------------------------------
// Kernel 2: projection GEMM, 128x128 tile, BK=64, 4 waves, fused fp32-A.
// ROUND-9 SINGLE CHANGE: attn-proven single-barrier double-buffered
// pipeline. R8 diagnosis: proj 109 us, MfmaUtil 19% -- two vmcnt-drain
// barriers per K-step with A-load latency fully exposed. Now: ONE barrier
// per K-step; staging of step k+1 (GLD16 B -> buf^1, cvt+ds_write A ->
// buf^1) happens at the BOTTOM after compute(k) (safe: all waves passed
// barrier(k), so none is still reading buf^1). A fp32 loads prefetched TWO
// steps deep in registers (full unroll -> static reg indices), so the cvt
// at write time never waits; only the barrier drain remains, covered by
// wave skew. LDS 64 KB = 2 bufs x (A 16K + B 16K) -> 2 blocks/CU.
// p=0: Q (scale folded), p=1: K, p=2: V (ReLU + [B,H,D,S] output).
// ---------------------------------------------------------------------------
__global__ __launch_bounds__(256) void proj_kernel(
    const float* __restrict__ qf, const float* __restrict__ kf,
    const float* __restrict__ vf, const unsigned short* __restrict__ WtBase,
    const float* __restrict__ bq, const float* __restrict__ bk, const float* __restrict__ bv,
    unsigned short* __restrict__ Qg, unsigned short* __restrict__ Kg,
    unsigned short* __restrict__ Vt)
{
    // buf b (shorts): A at b*16384, B at b*16384 + 8192. Epilogue Tsh reuses
    // [0, 17408) -- barrier before epilogue required (overlaps buf1 A head).
    __shared__ __align__(16) unsigned short smem[32768];   // 65536 B

    const int p = blockIdx.z;
    const float* Af = (p == 0) ? qf : (p == 1) ? kf : vf;   // fp32 [8192][1024]
    const unsigned short* Wp  = WtBase  + (size_t)p * (KD * EMB);
    const float* bias = (p == 0) ? bq : (p == 1) ? bk : bv;
    unsigned short* dst = (p == 0) ? Qg : (p == 1) ? Kg : Vt;

    const int row0 = blockIdx.x * 128;
    const int col0 = blockIdx.y * 128;
    const int t = threadIdx.x, lane = t & 63, wv = t >> 6;
    const int ln15 = lane & 15, q4 = lane >> 4;
    const int wm = wv & 1, wn = wv >> 1;

    f32x4 acc[4][4];
#pragma unroll
    for (int i = 0; i < 4; ++i)
#pragma unroll
        for (int j = 0; j < 4; ++j)
#pragma unroll
            for (int r = 0; r < 4; ++r) acc[i][j][r] = 0.f;

    const int lr = lane >> 3, lc = (lane & 7) ^ lr;
    const float*          gAf = Af + (size_t)(row0 + wv * 32 + lr) * KD + lc * 8;
    const unsigned short* gB  = Wp + (size_t)(col0 + wv * 32 + lr) * KD + lc * 8;
    const int lAoff = wv * 2048 + lane * 8;   // shorts, + i*512
    const int lBoff = 8192 + wv * 2048;       // shorts, + i*512 (GLD16 adds lane*16B)

    // A prefetch registers: [set][i][half]; fully unrolled -> static indices
    float4 aN[4][2];   // A(k+1) raw fp32
    float4 aF[4][2];   // A(k+2) raw fp32

    // ---- prologue: stage k=0 into buf0, prefetch A(1) ----
    {
        float4 a0[4][2];
#pragma unroll
        for (int i = 0; i < 4; ++i) {
            a0[i][0] = *(const float4*)(gAf + (size_t)i * 8 * KD + 0);
            a0[i][1] = *(const float4*)(gAf + (size_t)i * 8 * KD + 4);
        }
#pragma unroll
        for (int i = 0; i < 4; ++i)
            GLD16(gB + (size_t)i * 8 * KD + 0, smem + lBoff + i * 512);
#pragma unroll
        for (int i = 0; i < 4; ++i) {
            uint4 u;
            u.x = packbf(a0[i][0].x, a0[i][0].y); u.y = packbf(a0[i][0].z, a0[i][0].w);
            u.z = packbf(a0[i][1].x, a0[i][1].y); u.w = packbf(a0[i][1].z, a0[i][1].w);
            *(uint4*)&smem[lAoff + i * 512] = u;
        }
#pragma unroll
        for (int i = 0; i < 4; ++i) {
            aN[i][0] = *(const float4*)(gAf + (size_t)i * 8 * KD + 64);
            aN[i][1] = *(const float4*)(gAf + (size_t)i * 8 * KD + 64 + 4);
        }
    }

#pragma unroll
    for (int k0 = 0; k0 < 16; ++k0) {
        __syncthreads();   // buf(k0&1) fully staged (writes at bottom of k0-1 + drains)

        const unsigned short* Ab_ = smem + (k0 & 1) * 16384;
        const unsigned short* Bb_ = Ab_ + 8192;

#pragma unroll
        for (int kk = 0; kk < 2; ++kk) {
            short8 af[4], bfr[4];
#pragma unroll
            for (int mi = 0; mi < 4; ++mi) {
                const int r = wm * 64 + mi * 16 + ln15;
                af[mi] = *(const short8*)&Ab_[r * 64 + (((kk << 2) | q4) ^ (r & 7)) * 8];
            }
#pragma unroll
            for (int ni = 0; ni < 4; ++ni) {
                const int r = wn * 64 + ni * 16 + ln15;
                bfr[ni] = *(const short8*)&Bb_[r * 64 + (((kk << 2) | q4) ^ (r & 7)) * 8];
            }
#pragma unroll
            for (int mi = 0; mi < 4; ++mi)
#pragma unroll
                for (int ni = 0; ni < 4; ++ni)
                    acc[mi][ni] = __builtin_amdgcn_mfma_f32_16x16x32_bf16(
                        af[mi], bfr[ni], acc[mi][ni], 0, 0, 0);
        }

        // ---- bottom: stage k0+1 into buf^1 (all waves done reading it) ----
        if (k0 < 15) {
            unsigned short* dBuf = smem + ((k0 + 1) & 1) * 16384;
#pragma unroll
            for (int i = 0; i < 4; ++i)
                GLD16(gB + (size_t)i * 8 * KD + (k0 + 1) * 64, dBuf + lBoff + i * 512);
            if (k0 < 14) {
#pragma unroll
                for (int i = 0; i < 4; ++i) {
                    aF[i][0] = *(const float4*)(gAf + (size_t)i * 8 * KD + (k0 + 2) * 64);
                    aF[i][1] = *(const float4*)(gAf + (size_t)i * 8 * KD + (k0 + 2) * 64 + 4);
                }
            }
#pragma unroll
            for (int i = 0; i < 4; ++i) {
                uint4 u;
                u.x = packbf(aN[i][0].x, aN[i][0].y); u.y = packbf(aN[i][0].z, aN[i][0].w);
                u.z = packbf(aN[i][1].x, aN[i][1].y); u.w = packbf(aN[i][1].z, aN[i][1].w);
                *(uint4*)&dBuf[lAoff + i * 512] = u;
            }
#pragma unroll
            for (int i = 0; i < 4; ++i) { aN[i][0] = aF[i][0]; aN[i][1] = aF[i][1]; }
        }
    }
    __syncthreads();   // all compute done before Tsh overwrites smem

    float bvv[4];
#pragma unroll
    for (int ni = 0; ni < 4; ++ni) bvv[ni] = bias[col0 + wn * 64 + ni * 16 + ln15];
    const float scq = 0.18033688011112042f;   // log2(e)/sqrt(64), folded into Q

    unsigned short* Tsh = smem;   // [128][136]
#pragma unroll
    for (int mi = 0; mi < 4; ++mi)
#pragma unroll
        for (int ni = 0; ni < 4; ++ni)
#pragma unroll
            for (int r = 0; r < 4; ++r) {
                const int mr = wm * 64 + mi * 16 + q4 * 4 + r;
                const int ec = wn * 64 + ni * 16 + ln15;
                float vv = acc[mi][ni][r] + bvv[ni];
                if (p == 0) vv *= scq;
                if (p == 2) vv = vv > 0.f ? vv : 0.f;   // ReLU
                Tsh[mr * 136 + ec] = f2bf(vv);
            }
    __syncthreads();

    if (p < 2) {
        const int mr = t >> 1, hsel = t & 1;
        const int m = row0 + mr, bi = m >> 11, s = m & 2047;
        const int hh = (col0 >> 6) + hsel;
        const unsigned short* src = &Tsh[mr * 136 + hsel * 64];
        unsigned short* o = dst + ((size_t)(bi * NH + hh) * SEQ + s) * DH;
#pragma unroll
        for (int c = 0; c < 8; ++c)
            *(uint4*)(o + 8 * c) = *(const uint4*)(src + 8 * c);
    } else {
        const int e = t >> 1, sh2 = t & 1;
        const int n = col0 + e, hh = n >> 6, dd = n & 63;
        const int bi = row0 >> 11, sbase = (row0 & 2047) + sh2 * 64;
        unsigned ub[32];
#pragma unroll
        for (int i = 0; i < 32; ++i)
            ub[i] = (unsigned)Tsh[(sh2 * 64 + 2 * i) * 136 + e] |
                    ((unsigned)Tsh[(sh2 * 64 + 2 * i + 1) * 136 + e] << 16);
        unsigned short* o = dst + ((size_t)(bi * NH + hh) * DH + dd) * SEQ + sbase;
#pragma unroll
        for (int c = 0; c < 8; ++c)
            *(uint4*)(o + 8 * c) = uint4{ub[4 * c], ub[4 * c + 1], ub[4 * c + 2], ub[4 * c + 3]};
    }
}

// ---------------------------------------------------------------------------
// Kernel 3: flash attention, 32x32x16 bf16 mfma, S^T = K*Q^T formulation.
// EXACT round-5 proven structure (84.4 us): 8 waves/block (512 thr) sharing
// one double-buffered K/V tile, Q32/wave, ones-MFMA L, ONE barrier per iter,
// in-loop st zero-init, NO setprio (regressed twice), no-max exp2 softmax,
// XCD-locality remap (FETCH 143->25 MB proven).
// Grid: (8, 16, 4) = 512 blocks.
// ---------------------------------------------------------------------------
__global__ __launch_bounds__(512) void attn_kernel(
    const unsigned short* __restrict__ Qg, const unsigned short* __restrict__ Kg,
    const unsigned short* __restrict__ Vt, float* __restrict__ out)
{
    // buffer b: K at smem + b*9216, V at smem + b*9216 + 4608 (shorts, pitch 72)
    __shared__ __align__(16) unsigned short smem[18432];   // 36864 B

    // XCD-locality remap (bijective on 512 blocks; 8 q-blocks/head same XCD)
    const int lin = blockIdx.x + (blockIdx.y << 3) + (blockIdx.z << 7);
    const int g_xcd = lin & 7, s_lin = lin >> 3;        // s_lin 0..63
    const int qb = s_lin & 7;
    const int bh_idx = g_xcd + ((s_lin >> 3) << 3);     // 0..63
    const int hh = bh_idx & 15, bb = bh_idx >> 4;

    const int t = threadIdx.x, lane = t & 63, wv = t >> 6;   // wv 0..7
    const int ln31 = lane & 31, h2 = lane >> 5;
    const size_t bh = (size_t)(bb * NH + hh);
    const unsigned short* Qp = Qg + bh * (SEQ * DH);
    const unsigned short* Kp = Kg + bh * (SEQ * DH);
    const unsigned short* Vp = Vt + bh * (DH * SEQ);
    const int q0 = qb * 256 + wv * 32;

    short8 qf[4];
#pragma unroll
    for (int dc = 0; dc < 4; ++dc)
        qf[dc] = *(const short8*)(Qp + (size_t)(q0 + ln31) * DH + h2 * 8 + dc * 16);

    short8 ones;
#pragma unroll
    for (int i = 0; i < 8; ++i) ones[i] = (short)0x3F80;   // bf16 1.0

    f32x16 accO[2], accL;
#pragma unroll
    for (int i = 0; i < 16; ++i) { accO[0][i] = 0.f; accO[1][i] = 0.f; accL[i] = 0.f; }

    // staging: 512 threads, 16B each: thread -> K row srow (store permuted),
    // V^T row srow
    const int srow = t >> 3, sp = (t & 7) * 8;
    const int prow = srow ^ (((((srow >> 2) ^ (srow >> 3)) & 1)) ? 12 : 0);
    const unsigned short* gk = Kp + (size_t)srow * DH + sp;
    const unsigned short* gv = Vp + (size_t)srow * SEQ + sp;
    const int wkoff = prow * 72 + sp;           // K write offset within buffer
    const int wvoff = 4608 + srow * 72 + sp;    // V write offset within buffer

    {   // prologue: stage tile 0 into buffer 0
        short8 ka = *(const short8*)(gk);
        short8 va = *(const short8*)(gv);
        *(short8*)&smem[wkoff] = ka;
        *(short8*)&smem[wvoff] = va;
    }

    for (int it = 0; it < 32; ++it) {
        // issue next tile's global loads before the barrier (wraps at end)
        const int nxt = (it + 1) & 31;
        short8 ka = *(const short8*)(gk + (size_t)nxt * 64 * DH);
        short8 va = *(const short8*)(gv + nxt * 64);

        __syncthreads();   // buffer (it&1) fully staged by all waves

        const unsigned short* Ksh = smem + (it & 1) * 9216;
        const unsigned short* Vsh = Ksh + 4608;

        // S^T[key][q] = K·Q^T  (rows permuted via staging; Q pre-scaled)
        f32x16 st[2];
#pragma unroll
        for (int kt = 0; kt < 2; ++kt) {
#pragma unroll
            for (int i = 0; i < 16; ++i) st[kt][i] = 0.f;
#pragma unroll
            for (int dc = 0; dc < 4; ++dc) {
                short8 kf = *(const short8*)&Ksh[(kt * 32 + ln31) * 72 + h2 * 8 + dc * 16];
                st[kt] = __builtin_amdgcn_mfma_f32_32x32x16_bf16(kf, qf[dc], st[kt], 0, 0, 0);
            }
        }
        // P = exp2(S)  (no max subtraction: |S| bounded, fp32-safe)
#pragma unroll
        for (int kt = 0; kt < 2; ++kt)
#pragma unroll
            for (int r = 0; r < 16; ++r)
                st[kt][r] = __builtin_amdgcn_exp2f(st[kt][r]);

        // pf(kt,kc) = packed st regs [8kc..8kc+7] -- permutation makes these
        // exactly keys {16kc + h2*8 + 0..7} in order.  L += 1^T·P^T; O^T += V^T·P^T
#pragma unroll
        for (int kt = 0; kt < 2; ++kt)
#pragma unroll
            for (int kc = 0; kc < 2; ++kc) {
                union { unsigned u[4]; short8 v; } pf;
#pragma unroll
                for (int i = 0; i < 4; ++i)
                    pf.u[i] = packbf(st[kt][8 * kc + 2 * i], st[kt][8 * kc + 2 * i + 1]);
                accL = __builtin_amdgcn_mfma_f32_32x32x16_bf16(ones, pf.v, accL, 0, 0, 0);
#pragma unroll
                for (int dt = 0; dt < 2; ++dt) {
                    short8 vf = *(const short8*)&Vsh[(dt * 32 + ln31) * 72 + kt * 32 + kc * 16 + h2 * 8];
                    accO[dt] = __builtin_amdgcn_mfma_f32_32x32x16_bf16(vf, pf.v, accO[dt], 0, 0, 0);
                }
            }

        // stage next tile into the other buffer (safe: everyone left it at
        // the barrier above; readers of it re-sync at next iter's barrier)
        unsigned short* wbuf = smem + ((it + 1) & 1) * 9216;
        *(short8*)&wbuf[wkoff] = ka;
        *(short8*)&wbuf[wvoff] = va;
    }

    // epilogue: direct from AGPR C-layout.  lane q = q0+ln31; regs 4g+j of
    // accO[dt] are d = dt*32 + 4*h2 + 8*g + j  -> contiguous float4 chunks.
    const float inv = 1.0f / accL[0];
    float* orow = out + ((size_t)(bb * SEQ + q0 + ln31) * NH + hh) * 64;
#pragma unroll
    for (int dt = 0; dt < 2; ++dt)
#pragma unroll
        for (int g = 0; g < 4; ++g) {
            float4 w;
            w.x = accO[dt][4 * g + 0] * inv;
            w.y = accO[dt][4 * g + 1] * inv;
            w.z = accO[dt][4 * g + 2] * inv;
            w.w = accO[dt][4 * g + 3] * inv;
            *(float4*)(orow + dt * 32 + 4 * h2 + 8 * g) = w;
        }
}

// ---------------------------------------------------------------------------
extern "C" void kernel_launch(void* const* d_in, const int* in_sizes, int n_in,
                              void* d_out, int out_size, void* d_ws, size_t ws_size,
                              hipStream_t stream) {
    const float* qf = (const float*)d_in[0];
    const float* kf = (const float*)d_in[1];
    const float* vf = (const float*)d_in[2];
    const float* Wq = (const float*)d_in[3];
    const float* bq = (const float*)d_in[4];
    const float* Wk = (const float*)d_in[5];
    const float* bk = (const float*)d_in[6];
    const float* Wv = (const float*)d_in[7];
    const float* bv = (const float*)d_in[8];

    char* ws = (char*)d_ws;
    unsigned short* Wt  = (unsigned short*)ws;               // 6 MB
    unsigned short* Qg  = (unsigned short*)(ws + 6291456);   // 16 MB [B,H,S,D]
    unsigned short* Kg  = Qg + 8388608;                      // 16 MB [B,H,S,D]
    unsigned short* Vt  = Kg + 8388608;                      // 16 MB [B,H,D,S]
    float* out = (float*)d_out;

    wt_kernel<<<dim3(16, 16, 3), 256, 0, stream>>>(Wq, Wk, Wv, Wt);
    proj_kernel<<<dim3(64, 8, 3), 256, 0, stream>>>(qf, kf, vf, Wt, bq, bk, bv, Qg, Kg, Vt);
    attn_kernel<<<dim3(8, 16, 4), 512, 0, stream>>>(Qg, Kg, Vt, out);
}

// Round 10
// 314.130 us; speedup vs baseline: 1.0242x; 1.0242x over previous
//
#include <hip/hip_runtime.h>
#include <hip/hip_bf16.h>
#include <stdint.h>

// Problem constants
#define BB    4
#define NH    16
#define SEQ   2048
#define DH    64
#define EMB   1024
#define KD    1024
#define MROWS 8192   // BB*SEQ

typedef short  short8  __attribute__((ext_vector_type(8)));
typedef float  f32x4   __attribute__((ext_vector_type(4)));
typedef float  f32x16  __attribute__((ext_vector_type(16)));

typedef const __attribute__((address_space(1))) void* gas_t;
typedef __attribute__((address_space(3))) void*       las_t;
#define GLD16(g, l) __builtin_amdgcn_global_load_lds((gas_t)(g), (las_t)(l), 16, 0, 0)

__device__ __forceinline__ unsigned short f2bf(float f) {
    unsigned u = __float_as_uint(f);
    u += 0x7fffu + ((u >> 16) & 1u);   // RNE
    return (unsigned short)(u >> 16);
}
__device__ __forceinline__ unsigned packbf(float lo, float hi) {
    union { __hip_bfloat162 h; unsigned u; } cv;
    cv.h = __float22bfloat162_rn(make_float2(lo, hi));   // v_cvt_pk_bf16_f32
    return cv.u;
}

// ---------------------------------------------------------------------------
// Kernel 1: Wt[p][n][k] = bf16(W[p][k][n])
// ---------------------------------------------------------------------------
__global__ __launch_bounds__(256) void wt_kernel(const float* __restrict__ Wq,
                                                 const float* __restrict__ Wk,
                                                 const float* __restrict__ Wv,
                                                 unsigned short* __restrict__ Wt) {
    __shared__ float tsh[64 * 68];
    const int p = blockIdx.z;
    const float* W = (p == 0) ? Wq : (p == 1) ? Wk : Wv;
    unsigned short* dst = Wt + (size_t)p * (KD * EMB);
    const int k0 = blockIdx.x * 64, n0 = blockIdx.y * 64;
    const int t = threadIdx.x;
    {
        const int r = t >> 2, c4 = (t & 3) * 16;
        const float* g = W + (size_t)(k0 + r) * EMB + n0 + c4;
        float* row = &tsh[r * 68 + c4];
        *(float4*)(row + 0)  = *(const float4*)(g + 0);
        *(float4*)(row + 4)  = *(const float4*)(g + 4);
        *(float4*)(row + 8)  = *(const float4*)(g + 8);
        *(float4*)(row + 12) = *(const float4*)(g + 12);
    }
    __syncthreads();
    {
        const int j = t >> 2, kp = (t & 3) * 16;
        unsigned ub[8];
#pragma unroll
        for (int ii = 0; ii < 8; ++ii)
            ub[ii] = packbf(tsh[(kp + 2 * ii) * 68 + j], tsh[(kp + 2 * ii + 1) * 68 + j]);
        unsigned short* o = dst + (size_t)(n0 + j) * KD + k0 + kp;
        *(uint4*)(o + 0) = uint4{ub[0], ub[1], ub[2], ub[3]};
        *(uint4*)(o + 8) = uint4{ub[4], ub[5], ub[6], ub[7]};
    }
}

// ---------------------------------------------------------------------------
// Kernel 2: projection GEMM, 128x128 tile, BK=64, 4 waves, fused fp32-A.
// Structure = R8 exact (109 us proven: single LDS buffer, two barriers per
// K-step, GLD16 B, reg-staged fp32 A + cvt + ds_write, 34816 B LDS ->
// 4 blocks/CU).
// ROUND-10 SINGLE CHANGE: 1-step A register prefetch issued AFTER barrier1
// (top of compute k). R9 lesson: __syncthreads drains vmcnt(0), so loads
// issued at the bottom are 100% exposed at the next barrier; loads issued
// after barrier1 drain at barrier2 -- i.e. UNDER the 128-MFMA compute
// phase. The stage phase's serial chain (load->wait->cvt->write) becomes
// (cvt->write) with data already in regs. GLD16-B exposure at barrier1
// unchanged (single variable).
// p=0: Q (scale folded), p=1: K, p=2: V (ReLU + [B,H,D,S] output).
// ---------------------------------------------------------------------------
__global__ __launch_bounds__(256) void proj_kernel(
    const float* __restrict__ qf, const float* __restrict__ kf,
    const float* __restrict__ vf, const unsigned short* __restrict__ WtBase,
    const float* __restrict__ bq, const float* __restrict__ bk, const float* __restrict__ bv,
    unsigned short* __restrict__ Qg, unsigned short* __restrict__ Kg,
    unsigned short* __restrict__ Vt)
{
    __shared__ __align__(16) unsigned short smem[17408]; // A+B tiles 16384 U Tsh[128][136]
    unsigned short* Ash = smem;          // [128][64] swizzled
    unsigned short* Bsh = smem + 8192;   // [128][64] swizzled

    const int p = blockIdx.z;
    const float* Af = (p == 0) ? qf : (p == 1) ? kf : vf;   // fp32 [8192][1024]
    const unsigned short* Wp  = WtBase  + (size_t)p * (KD * EMB);
    const float* bias = (p == 0) ? bq : (p == 1) ? bk : bv;
    unsigned short* dst = (p == 0) ? Qg : (p == 1) ? Kg : Vt;

    const int row0 = blockIdx.x * 128;
    const int col0 = blockIdx.y * 128;
    const int t = threadIdx.x, lane = t & 63, wv = t >> 6;
    const int ln15 = lane & 15, q4 = lane >> 4;
    const int wm = wv & 1, wn = wv >> 1;

    f32x4 acc[4][4];
#pragma unroll
    for (int i = 0; i < 4; ++i)
#pragma unroll
        for (int j = 0; j < 4; ++j)
#pragma unroll
            for (int r = 0; r < 4; ++r) acc[i][j][r] = 0.f;

    const int lr = lane >> 3, lc = (lane & 7) ^ lr;
    const float*          gAf = Af + (size_t)(row0 + wv * 32 + lr) * KD + lc * 8;
    const unsigned short* gB  = Wp + (size_t)(col0 + wv * 32 + lr) * KD + lc * 8;
    unsigned short* lA = Ash + wv * 32 * 64;
    unsigned short* lB = Bsh + wv * 32 * 64;

    // A prefetch registers (1 step deep): data for the NEXT stage phase
    float4 aN[4][2];
#pragma unroll
    for (int i = 0; i < 4; ++i) {   // prologue: A(0) -> regs
        aN[i][0] = *(const float4*)(gAf + (size_t)i * 8 * KD + 0);
        aN[i][1] = *(const float4*)(gAf + (size_t)i * 8 * KD + 4);
    }

    for (int k0 = 0; k0 < KD; k0 += 64) {
        // ---- stage phase: B via DMA, A from prefetch regs (immediate) ----
#pragma unroll
        for (int i = 0; i < 4; ++i)
            GLD16(gB + (size_t)i * 8 * KD + k0, lB + i * 512);
#pragma unroll
        for (int i = 0; i < 4; ++i) {
            uint4 u;
            u.x = packbf(aN[i][0].x, aN[i][0].y); u.y = packbf(aN[i][0].z, aN[i][0].w);
            u.z = packbf(aN[i][1].x, aN[i][1].y); u.w = packbf(aN[i][1].z, aN[i][1].w);
            *(uint4*)&lA[i * 512 + lane * 8] = u;
        }
        __syncthreads();   // barrier1: drains GLD16 B(k0) + A ds_writes

        // issue A(k0+64) loads NOW: they drain at barrier2, under compute
        if (k0 < KD - 64) {
#pragma unroll
            for (int i = 0; i < 4; ++i) {
                aN[i][0] = *(const float4*)(gAf + (size_t)i * 8 * KD + k0 + 64);
                aN[i][1] = *(const float4*)(gAf + (size_t)i * 8 * KD + k0 + 68);
            }
        }

        // ---- compute phase ----
#pragma unroll
        for (int kk = 0; kk < 2; ++kk) {
            short8 af[4], bfr[4];
#pragma unroll
            for (int mi = 0; mi < 4; ++mi) {
                const int r = wm * 64 + mi * 16 + ln15;
                af[mi] = *(const short8*)&Ash[r * 64 + (((kk << 2) | q4) ^ (r & 7)) * 8];
            }
#pragma unroll
            for (int ni = 0; ni < 4; ++ni) {
                const int r = wn * 64 + ni * 16 + ln15;
                bfr[ni] = *(const short8*)&Bsh[r * 64 + (((kk << 2) | q4) ^ (r & 7)) * 8];
            }
#pragma unroll
            for (int mi = 0; mi < 4; ++mi)
#pragma unroll
                for (int ni = 0; ni < 4; ++ni)
                    acc[mi][ni] = __builtin_amdgcn_mfma_f32_16x16x32_bf16(
                        af[mi], bfr[ni], acc[mi][ni], 0, 0, 0);
        }
        __syncthreads();   // barrier2: protects buffer overwrite at next stage
    }

    float bvv[4];
#pragma unroll
    for (int ni = 0; ni < 4; ++ni) bvv[ni] = bias[col0 + wn * 64 + ni * 16 + ln15];
    const float scq = 0.18033688011112042f;   // log2(e)/sqrt(64), folded into Q

    unsigned short* Tsh = smem;   // [128][136]
#pragma unroll
    for (int mi = 0; mi < 4; ++mi)
#pragma unroll
        for (int ni = 0; ni < 4; ++ni)
#pragma unroll
            for (int r = 0; r < 4; ++r) {
                const int mr = wm * 64 + mi * 16 + q4 * 4 + r;
                const int ec = wn * 64 + ni * 16 + ln15;
                float vv = acc[mi][ni][r] + bvv[ni];
                if (p == 0) vv *= scq;
                if (p == 2) vv = vv > 0.f ? vv : 0.f;   // ReLU
                Tsh[mr * 136 + ec] = f2bf(vv);
            }
    __syncthreads();

    if (p < 2) {
        const int mr = t >> 1, hsel = t & 1;
        const int m = row0 + mr, bi = m >> 11, s = m & 2047;
        const int hh = (col0 >> 6) + hsel;
        const unsigned short* src = &Tsh[mr * 136 + hsel * 64];
        unsigned short* o = dst + ((size_t)(bi * NH + hh) * SEQ + s) * DH;
#pragma unroll
        for (int c = 0; c < 8; ++c)
            *(uint4*)(o + 8 * c) = *(const uint4*)(src + 8 * c);
    } else {
        const int e = t >> 1, sh2 = t & 1;
        const int n = col0 + e, hh = n >> 6, dd = n & 63;
        const int bi = row0 >> 11, sbase = (row0 & 2047) + sh2 * 64;
        unsigned ub[32];
#pragma unroll
        for (int i = 0; i < 32; ++i)
            ub[i] = (unsigned)Tsh[(sh2 * 64 + 2 * i) * 136 + e] |
                    ((unsigned)Tsh[(sh2 * 64 + 2 * i + 1) * 136 + e] << 16);
        unsigned short* o = dst + ((size_t)(bi * NH + hh) * DH + dd) * SEQ + sbase;
#pragma unroll
        for (int c = 0; c < 8; ++c)
            *(uint4*)(o + 8 * c) = uint4{ub[4 * c], ub[4 * c + 1], ub[4 * c + 2], ub[4 * c + 3]};
    }
}

// ---------------------------------------------------------------------------
// Kernel 3: flash attention, 32x32x16 bf16 mfma, S^T = K*Q^T formulation.
// EXACT round-5 proven structure (84.4 us): 8 waves/block (512 thr) sharing
// one double-buffered K/V tile, Q32/wave, ones-MFMA L, ONE barrier per iter,
// in-loop st zero-init, NO setprio (regressed twice), no-max exp2 softmax,
// XCD-locality remap (FETCH 143->25 MB proven).
// Grid: (8, 16, 4) = 512 blocks.
// ---------------------------------------------------------------------------
__global__ __launch_bounds__(512) void attn_kernel(
    const unsigned short* __restrict__ Qg, const unsigned short* __restrict__ Kg,
    const unsigned short* __restrict__ Vt, float* __restrict__ out)
{
    // buffer b: K at smem + b*9216, V at smem + b*9216 + 4608 (shorts, pitch 72)
    __shared__ __align__(16) unsigned short smem[18432];   // 36864 B

    // XCD-locality remap (bijective on 512 blocks; 8 q-blocks/head same XCD)
    const int lin = blockIdx.x + (blockIdx.y << 3) + (blockIdx.z << 7);
    const int g_xcd = lin & 7, s_lin = lin >> 3;        // s_lin 0..63
    const int qb = s_lin & 7;
    const int bh_idx = g_xcd + ((s_lin >> 3) << 3);     // 0..63
    const int hh = bh_idx & 15, bb = bh_idx >> 4;

    const int t = threadIdx.x, lane = t & 63, wv = t >> 6;   // wv 0..7
    const int ln31 = lane & 31, h2 = lane >> 5;
    const size_t bh = (size_t)(bb * NH + hh);
    const unsigned short* Qp = Qg + bh * (SEQ * DH);
    const unsigned short* Kp = Kg + bh * (SEQ * DH);
    const unsigned short* Vp = Vt + bh * (DH * SEQ);
    const int q0 = qb * 256 + wv * 32;

    short8 qf[4];
#pragma unroll
    for (int dc = 0; dc < 4; ++dc)
        qf[dc] = *(const short8*)(Qp + (size_t)(q0 + ln31) * DH + h2 * 8 + dc * 16);

    short8 ones;
#pragma unroll
    for (int i = 0; i < 8; ++i) ones[i] = (short)0x3F80;   // bf16 1.0

    f32x16 accO[2], accL;
#pragma unroll
    for (int i = 0; i < 16; ++i) { accO[0][i] = 0.f; accO[1][i] = 0.f; accL[i] = 0.f; }

    // staging: 512 threads, 16B each: thread -> K row srow (store permuted),
    // V^T row srow
    const int srow = t >> 3, sp = (t & 7) * 8;
    const int prow = srow ^ (((((srow >> 2) ^ (srow >> 3)) & 1)) ? 12 : 0);
    const unsigned short* gk = Kp + (size_t)srow * DH + sp;
    const unsigned short* gv = Vp + (size_t)srow * SEQ + sp;
    const int wkoff = prow * 72 + sp;           // K write offset within buffer
    const int wvoff = 4608 + srow * 72 + sp;    // V write offset within buffer

    {   // prologue: stage tile 0 into buffer 0
        short8 ka = *(const short8*)(gk);
        short8 va = *(const short8*)(gv);
        *(short8*)&smem[wkoff] = ka;
        *(short8*)&smem[wvoff] = va;
    }

    for (int it = 0; it < 32; ++it) {
        // issue next tile's global loads before the barrier (wraps at end)
        const int nxt = (it + 1) & 31;
        short8 ka = *(const short8*)(gk + (size_t)nxt * 64 * DH);
        short8 va = *(const short8*)(gv + nxt * 64);

        __syncthreads();   // buffer (it&1) fully staged by all waves

        const unsigned short* Ksh = smem + (it & 1) * 9216;
        const unsigned short* Vsh = Ksh + 4608;

        // S^T[key][q] = K·Q^T  (rows permuted via staging; Q pre-scaled)
        f32x16 st[2];
#pragma unroll
        for (int kt = 0; kt < 2; ++kt) {
#pragma unroll
            for (int i = 0; i < 16; ++i) st[kt][i] = 0.f;
#pragma unroll
            for (int dc = 0; dc < 4; ++dc) {
                short8 kf = *(const short8*)&Ksh[(kt * 32 + ln31) * 72 + h2 * 8 + dc * 16];
                st[kt] = __builtin_amdgcn_mfma_f32_32x32x16_bf16(kf, qf[dc], st[kt], 0, 0, 0);
            }
        }
        // P = exp2(S)  (no max subtraction: |S| bounded, fp32-safe)
#pragma unroll
        for (int kt = 0; kt < 2; ++kt)
#pragma unroll
            for (int r = 0; r < 16; ++r)
                st[kt][r] = __builtin_amdgcn_exp2f(st[kt][r]);

        // pf(kt,kc) = packed st regs [8kc..8kc+7] -- permutation makes these
        // exactly keys {16kc + h2*8 + 0..7} in order.  L += 1^T·P^T; O^T += V^T·P^T
#pragma unroll
        for (int kt = 0; kt < 2; ++kt)
#pragma unroll
            for (int kc = 0; kc < 2; ++kc) {
                union { unsigned u[4]; short8 v; } pf;
#pragma unroll
                for (int i = 0; i < 4; ++i)
                    pf.u[i] = packbf(st[kt][8 * kc + 2 * i], st[kt][8 * kc + 2 * i + 1]);
                accL = __builtin_amdgcn_mfma_f32_32x32x16_bf16(ones, pf.v, accL, 0, 0, 0);
#pragma unroll
                for (int dt = 0; dt < 2; ++dt) {
                    short8 vf = *(const short8*)&Vsh[(dt * 32 + ln31) * 72 + kt * 32 + kc * 16 + h2 * 8];
                    accO[dt] = __builtin_amdgcn_mfma_f32_32x32x16_bf16(vf, pf.v, accO[dt], 0, 0, 0);
                }
            }

        // stage next tile into the other buffer (safe: everyone left it at
        // the barrier above; readers of it re-sync at next iter's barrier)
        unsigned short* wbuf = smem + ((it + 1) & 1) * 9216;
        *(short8*)&wbuf[wkoff] = ka;
        *(short8*)&wbuf[wvoff] = va;
    }

    // epilogue: direct from AGPR C-layout.  lane q = q0+ln31; regs 4g+j of
    // accO[dt] are d = dt*32 + 4*h2 + 8*g + j  -> contiguous float4 chunks.
    const float inv = 1.0f / accL[0];
    float* orow = out + ((size_t)(bb * SEQ + q0 + ln31) * NH + hh) * 64;
#pragma unroll
    for (int dt = 0; dt < 2; ++dt)
#pragma unroll
        for (int g = 0; g < 4; ++g) {
            float4 w;
            w.x = accO[dt][4 * g + 0] * inv;
            w.y = accO[dt][4 * g + 1] * inv;
            w.z = accO[dt][4 * g + 2] * inv;
            w.w = accO[dt][4 * g + 3] * inv;
            *(float4*)(orow + dt * 32 + 4 * h2 + 8 * g) = w;
        }
}

// ---------------------------------------------------------------------------
extern "C" void kernel_launch(void* const* d_in, const int* in_sizes, int n_in,
                              void* d_out, int out_size, void* d_ws, size_t ws_size,
                              hipStream_t stream) {
    const float* qf = (const float*)d_in[0];
    const float* kf = (const float*)d_in[1];
    const float* vf = (const float*)d_in[2];
    const float* Wq = (const float*)d_in[3];
    const float* bq = (const float*)d_in[4];
    const float* Wk = (const float*)d_in[5];
    const float* bk = (const float*)d_in[6];
    const float* Wv = (const float*)d_in[7];
    const float* bv = (const float*)d_in[8];

    char* ws = (char*)d_ws;
    unsigned short* Wt  = (unsigned short*)ws;               // 6 MB
    unsigned short* Qg  = (unsigned short*)(ws + 6291456);   // 16 MB [B,H,S,D]
    unsigned short* Kg  = Qg + 8388608;                      // 16 MB [B,H,S,D]
    unsigned short* Vt  = Kg + 8388608;                      // 16 MB [B,H,D,S]
    float* out = (float*)d_out;

    wt_kernel<<<dim3(16, 16, 3), 256, 0, stream>>>(Wq, Wk, Wv, Wt);
    proj_kernel<<<dim3(64, 8, 3), 256, 0, stream>>>(qf, kf, vf, Wt, bq, bk, bv, Qg, Kg, Vt);
    attn_kernel<<<dim3(8, 16, 4), 512, 0, stream>>>(Qg, Kg, Vt, out);
}

// Round 11
// 303.792 us; speedup vs baseline: 1.0590x; 1.0340x over previous
//
#include <hip/hip_runtime.h>
#include <hip/hip_bf16.h>
#include <stdint.h>

// Problem constants
#define BB    4
#define NH    16
#define SEQ   2048
#define DH    64
#define EMB   1024
#define KD    1024
#define MROWS 8192   // BB*SEQ

typedef short  short8  __attribute__((ext_vector_type(8)));
typedef float  f32x4   __attribute__((ext_vector_type(4)));
typedef float  f32x16  __attribute__((ext_vector_type(16)));

typedef const __attribute__((address_space(1))) void* gas_t;
typedef __attribute__((address_space(3))) void*       las_t;
#define GLD16(g, l) __builtin_amdgcn_global_load_lds((gas_t)(g), (las_t)(l), 16, 0, 0)

__device__ __forceinline__ unsigned short f2bf(float f) {
    unsigned u = __float_as_uint(f);
    u += 0x7fffu + ((u >> 16) & 1u);   // RNE
    return (unsigned short)(u >> 16);
}
__device__ __forceinline__ unsigned packbf(float lo, float hi) {
    union { __hip_bfloat162 h; unsigned u; } cv;
    cv.h = __float22bfloat162_rn(make_float2(lo, hi));   // v_cvt_pk_bf16_f32
    return cv.u;
}

// ---------------------------------------------------------------------------
// Kernel 1: Wt[p][n][k] = bf16(W[p][k][n])
// ---------------------------------------------------------------------------
__global__ __launch_bounds__(256) void wt_kernel(const float* __restrict__ Wq,
                                                 const float* __restrict__ Wk,
                                                 const float* __restrict__ Wv,
                                                 unsigned short* __restrict__ Wt) {
    __shared__ float tsh[64 * 68];
    const int p = blockIdx.z;
    const float* W = (p == 0) ? Wq : (p == 1) ? Wk : Wv;
    unsigned short* dst = Wt + (size_t)p * (KD * EMB);
    const int k0 = blockIdx.x * 64, n0 = blockIdx.y * 64;
    const int t = threadIdx.x;
    {
        const int r = t >> 2, c4 = (t & 3) * 16;
        const float* g = W + (size_t)(k0 + r) * EMB + n0 + c4;
        float* row = &tsh[r * 68 + c4];
        *(float4*)(row + 0)  = *(const float4*)(g + 0);
        *(float4*)(row + 4)  = *(const float4*)(g + 4);
        *(float4*)(row + 8)  = *(const float4*)(g + 8);
        *(float4*)(row + 12) = *(const float4*)(g + 12);
    }
    __syncthreads();
    {
        const int j = t >> 2, kp = (t & 3) * 16;
        unsigned ub[8];
#pragma unroll
        for (int ii = 0; ii < 8; ++ii)
            ub[ii] = packbf(tsh[(kp + 2 * ii) * 68 + j], tsh[(kp + 2 * ii + 1) * 68 + j]);
        unsigned short* o = dst + (size_t)(n0 + j) * KD + k0 + kp;
        *(uint4*)(o + 0) = uint4{ub[0], ub[1], ub[2], ub[3]};
        *(uint4*)(o + 8) = uint4{ub[4], ub[5], ub[6], ub[7]};
    }
}

// ---------------------------------------------------------------------------
// Kernel 2: projection GEMM, fused fp32-A.
// ROUND-11 SINGLE CHANGE vs R8: tile 128x128 -> 128x256, 8 waves (512 thr),
// R8's exact two-barrier schedule otherwise (R9/R10 proved scheduling
// tweaks can't help: the 160-cycle compute phase is shorter than the
// 200-900-cycle latencies it must hide; the fix is MORE WORK PER BARRIER).
// MFMA per barrier interval doubles, barrier intervals halve (768 blocks),
// per-thread A-staging VALU halves. Per-wave inner loop unchanged (64x64
// out, acc 4x4, same XOR swizzle); waves on a 2x4 (row x col) grid.
// LDS 48KB = A[128][64] + B[256][64] (union w/ Tsh[128][136]).
// Epilogue: two 128-col half-passes through the proven Tsh path.
// p=0: Q (scale folded), p=1: K, p=2: V (ReLU + [B,H,D,S] output).
// ---------------------------------------------------------------------------
__global__ __launch_bounds__(512) void proj_kernel(
    const float* __restrict__ qf, const float* __restrict__ kf,
    const float* __restrict__ vf, const unsigned short* __restrict__ WtBase,
    const float* __restrict__ bq, const float* __restrict__ bk, const float* __restrict__ bv,
    unsigned short* __restrict__ Qg, unsigned short* __restrict__ Kg,
    unsigned short* __restrict__ Vt)
{
    // Ash [128][64] = 8192 shorts; Bsh [256][64] = 16384 shorts; union Tsh[128][136]
    __shared__ __align__(16) unsigned short smem[24576];   // 49152 B
    unsigned short* Ash = smem;
    unsigned short* Bsh = smem + 8192;

    const int p = blockIdx.z;
    const float* Af = (p == 0) ? qf : (p == 1) ? kf : vf;   // fp32 [8192][1024]
    const unsigned short* Wp  = WtBase  + (size_t)p * (KD * EMB);
    const float* bias = (p == 0) ? bq : (p == 1) ? bk : bv;
    unsigned short* dst = (p == 0) ? Qg : (p == 1) ? Kg : Vt;

    const int row0 = blockIdx.x * 128;
    const int col0 = blockIdx.y * 256;
    const int t = threadIdx.x, lane = t & 63, wv = t >> 6;   // wv 0..7
    const int ln15 = lane & 15, q4 = lane >> 4;
    const int wm = wv & 1, wn = wv >> 1;        // wave: row-half x col-quarter
    const int wva = wv >> 1;                    // A-staging group (4 x 32 rows)

    f32x4 acc[4][4];
#pragma unroll
    for (int i = 0; i < 4; ++i)
#pragma unroll
        for (int j = 0; j < 4; ++j)
#pragma unroll
            for (int r = 0; r < 4; ++r) acc[i][j][r] = 0.f;

    const int lr = lane >> 3, lc = (lane & 7) ^ lr;
    const float*          gAf = Af + (size_t)(row0 + wva * 32 + lr) * KD + lc * 8;
    const unsigned short* gB  = Wp + (size_t)(col0 + wv * 32 + lr) * KD + lc * 8;
    unsigned short* lB = Bsh + wv * 32 * 64;

    for (int k0 = 0; k0 < KD; k0 += 64) {
        // ---- stage: B via DMA (wv covers 256 rows), A fp32->bf16 (wva) ----
#pragma unroll
        for (int i = 0; i < 4; ++i)
            GLD16(gB + (size_t)i * 8 * KD + k0, lB + i * 512);
#pragma unroll
        for (int j = 0; j < 2; ++j) {
            const int i2 = (wv & 1) * 2 + j;
            float4 a0 = *(const float4*)(gAf + (size_t)i2 * 8 * KD + k0);
            float4 a1 = *(const float4*)(gAf + (size_t)i2 * 8 * KD + k0 + 4);
            uint4 u;
            u.x = packbf(a0.x, a0.y); u.y = packbf(a0.z, a0.w);
            u.z = packbf(a1.x, a1.y); u.w = packbf(a1.z, a1.w);
            *(uint4*)&Ash[wva * 2048 + i2 * 512 + lane * 8] = u;
        }
        __syncthreads();   // barrier1: drains GLD16 B + A ds_writes

        // ---- compute: 2 x (4x4) mfma per wave, 64x64 out at (wm, wn) ----
#pragma unroll
        for (int kk = 0; kk < 2; ++kk) {
            short8 af[4], bfr[4];
#pragma unroll
            for (int mi = 0; mi < 4; ++mi) {
                const int r = wm * 64 + mi * 16 + ln15;
                af[mi] = *(const short8*)&Ash[r * 64 + (((kk << 2) | q4) ^ (r & 7)) * 8];
            }
#pragma unroll
            for (int ni = 0; ni < 4; ++ni) {
                const int r = wn * 64 + ni * 16 + ln15;
                bfr[ni] = *(const short8*)&Bsh[r * 64 + (((kk << 2) | q4) ^ (r & 7)) * 8];
            }
#pragma unroll
            for (int mi = 0; mi < 4; ++mi)
#pragma unroll
                for (int ni = 0; ni < 4; ++ni)
                    acc[mi][ni] = __builtin_amdgcn_mfma_f32_16x16x32_bf16(
                        af[mi], bfr[ni], acc[mi][ni], 0, 0, 0);
        }
        __syncthreads();   // barrier2: protects buffer overwrite at next stage
    }

    float bvv[4];
#pragma unroll
    for (int ni = 0; ni < 4; ++ni) bvv[ni] = bias[col0 + wn * 64 + ni * 16 + ln15];
    const float scq = 0.18033688011112042f;   // log2(e)/sqrt(64), folded into Q

    // ---- epilogue: two 128-col half-passes through Tsh[128][136] ----
    unsigned short* Tsh = smem;
#pragma unroll
    for (int h = 0; h < 2; ++h) {
        __syncthreads();   // h=0: sep from K-loop; h=1: prev stores done
        if ((wn >> 1) == h) {
            const int ecb = (wn & 1) * 64;
#pragma unroll
            for (int mi = 0; mi < 4; ++mi)
#pragma unroll
                for (int ni = 0; ni < 4; ++ni)
#pragma unroll
                    for (int r = 0; r < 4; ++r) {
                        const int mr = wm * 64 + mi * 16 + q4 * 4 + r;
                        const int ec = ecb + ni * 16 + ln15;
                        float vv = acc[mi][ni][r] + bvv[ni];
                        if (p == 0) vv *= scq;
                        if (p == 2) vv = vv > 0.f ? vv : 0.f;   // ReLU
                        Tsh[mr * 136 + ec] = f2bf(vv);
                    }
        }
        __syncthreads();

        if (p < 2) {
            const int mr = t >> 2, sub = t & 3, hsel = sub >> 1, qtr = sub & 1;
            const int m = row0 + mr, bi = m >> 11, s = m & 2047;
            const int hh = (col0 >> 6) + h * 2 + hsel;
            const unsigned short* src = &Tsh[mr * 136 + hsel * 64 + qtr * 32];
            unsigned short* o = dst + ((size_t)(bi * NH + hh) * SEQ + s) * DH + qtr * 32;
#pragma unroll
            for (int c = 0; c < 4; ++c)
                *(uint4*)(o + 8 * c) = *(const uint4*)(src + 8 * c);
        } else {
            const int e = t >> 2, sub = t & 3, sh2 = sub >> 1, qtr = sub & 1;
            const int n = col0 + h * 128 + e, hhv = n >> 6, dd = n & 63;
            const int bi = row0 >> 11;
            const int sbase = (row0 & 2047) + sh2 * 64 + qtr * 32;
            unsigned ub[16];
#pragma unroll
            for (int i = 0; i < 16; ++i)
                ub[i] = (unsigned)Tsh[(sh2 * 64 + qtr * 32 + 2 * i) * 136 + e] |
                        ((unsigned)Tsh[(sh2 * 64 + qtr * 32 + 2 * i + 1) * 136 + e] << 16);
            unsigned short* o = dst + ((size_t)(bi * NH + hhv) * DH + dd) * SEQ + sbase;
#pragma unroll
            for (int c = 0; c < 4; ++c)
                *(uint4*)(o + 8 * c) = uint4{ub[4 * c], ub[4 * c + 1], ub[4 * c + 2], ub[4 * c + 3]};
        }
    }
}

// ---------------------------------------------------------------------------
// Kernel 3: flash attention, 32x32x16 bf16 mfma, S^T = K*Q^T formulation.
// EXACT round-5 proven structure (84.4 us): 8 waves/block (512 thr) sharing
// one double-buffered K/V tile, Q32/wave, ones-MFMA L, ONE barrier per iter,
// in-loop st zero-init, NO setprio (regressed twice), no-max exp2 softmax,
// XCD-locality remap (FETCH 143->25 MB proven).
// Grid: (8, 16, 4) = 512 blocks.
// ---------------------------------------------------------------------------
__global__ __launch_bounds__(512) void attn_kernel(
    const unsigned short* __restrict__ Qg, const unsigned short* __restrict__ Kg,
    const unsigned short* __restrict__ Vt, float* __restrict__ out)
{
    // buffer b: K at smem + b*9216, V at smem + b*9216 + 4608 (shorts, pitch 72)
    __shared__ __align__(16) unsigned short smem[18432];   // 36864 B

    // XCD-locality remap (bijective on 512 blocks; 8 q-blocks/head same XCD)
    const int lin = blockIdx.x + (blockIdx.y << 3) + (blockIdx.z << 7);
    const int g_xcd = lin & 7, s_lin = lin >> 3;        // s_lin 0..63
    const int qb = s_lin & 7;
    const int bh_idx = g_xcd + ((s_lin >> 3) << 3);     // 0..63
    const int hh = bh_idx & 15, bb = bh_idx >> 4;

    const int t = threadIdx.x, lane = t & 63, wv = t >> 6;   // wv 0..7
    const int ln31 = lane & 31, h2 = lane >> 5;
    const size_t bh = (size_t)(bb * NH + hh);
    const unsigned short* Qp = Qg + bh * (SEQ * DH);
    const unsigned short* Kp = Kg + bh * (SEQ * DH);
    const unsigned short* Vp = Vt + bh * (DH * SEQ);
    const int q0 = qb * 256 + wv * 32;

    short8 qf[4];
#pragma unroll
    for (int dc = 0; dc < 4; ++dc)
        qf[dc] = *(const short8*)(Qp + (size_t)(q0 + ln31) * DH + h2 * 8 + dc * 16);

    short8 ones;
#pragma unroll
    for (int i = 0; i < 8; ++i) ones[i] = (short)0x3F80;   // bf16 1.0

    f32x16 accO[2], accL;
#pragma unroll
    for (int i = 0; i < 16; ++i) { accO[0][i] = 0.f; accO[1][i] = 0.f; accL[i] = 0.f; }

    // staging: 512 threads, 16B each: thread -> K row srow (store permuted),
    // V^T row srow
    const int srow = t >> 3, sp = (t & 7) * 8;
    const int prow = srow ^ (((((srow >> 2) ^ (srow >> 3)) & 1)) ? 12 : 0);
    const unsigned short* gk = Kp + (size_t)srow * DH + sp;
    const unsigned short* gv = Vp + (size_t)srow * SEQ + sp;
    const int wkoff = prow * 72 + sp;           // K write offset within buffer
    const int wvoff = 4608 + srow * 72 + sp;    // V write offset within buffer

    {   // prologue: stage tile 0 into buffer 0
        short8 ka = *(const short8*)(gk);
        short8 va = *(const short8*)(gv);
        *(short8*)&smem[wkoff] = ka;
        *(short8*)&smem[wvoff] = va;
    }

    for (int it = 0; it < 32; ++it) {
        // issue next tile's global loads before the barrier (wraps at end)
        const int nxt = (it + 1) & 31;
        short8 ka = *(const short8*)(gk + (size_t)nxt * 64 * DH);
        short8 va = *(const short8*)(gv + nxt * 64);

        __syncthreads();   // buffer (it&1) fully staged by all waves

        const unsigned short* Ksh = smem + (it & 1) * 9216;
        const unsigned short* Vsh = Ksh + 4608;

        // S^T[key][q] = K·Q^T  (rows permuted via staging; Q pre-scaled)
        f32x16 st[2];
#pragma unroll
        for (int kt = 0; kt < 2; ++kt) {
#pragma unroll
            for (int i = 0; i < 16; ++i) st[kt][i] = 0.f;
#pragma unroll
            for (int dc = 0; dc < 4; ++dc) {
                short8 kf = *(const short8*)&Ksh[(kt * 32 + ln31) * 72 + h2 * 8 + dc * 16];
                st[kt] = __builtin_amdgcn_mfma_f32_32x32x16_bf16(kf, qf[dc], st[kt], 0, 0, 0);
            }
        }
        // P = exp2(S)  (no max subtraction: |S| bounded, fp32-safe)
#pragma unroll
        for (int kt = 0; kt < 2; ++kt)
#pragma unroll
            for (int r = 0; r < 16; ++r)
                st[kt][r] = __builtin_amdgcn_exp2f(st[kt][r]);

        // pf(kt,kc) = packed st regs [8kc..8kc+7] -- permutation makes these
        // exactly keys {16kc + h2*8 + 0..7} in order.  L += 1^T·P^T; O^T += V^T·P^T
#pragma unroll
        for (int kt = 0; kt < 2; ++kt)
#pragma unroll
            for (int kc = 0; kc < 2; ++kc) {
                union { unsigned u[4]; short8 v; } pf;
#pragma unroll
                for (int i = 0; i < 4; ++i)
                    pf.u[i] = packbf(st[kt][8 * kc + 2 * i], st[kt][8 * kc + 2 * i + 1]);
                accL = __builtin_amdgcn_mfma_f32_32x32x16_bf16(ones, pf.v, accL, 0, 0, 0);
#pragma unroll
                for (int dt = 0; dt < 2; ++dt) {
                    short8 vf = *(const short8*)&Vsh[(dt * 32 + ln31) * 72 + kt * 32 + kc * 16 + h2 * 8];
                    accO[dt] = __builtin_amdgcn_mfma_f32_32x32x16_bf16(vf, pf.v, accO[dt], 0, 0, 0);
                }
            }

        // stage next tile into the other buffer (safe: everyone left it at
        // the barrier above; readers of it re-sync at next iter's barrier)
        unsigned short* wbuf = smem + ((it + 1) & 1) * 9216;
        *(short8*)&wbuf[wkoff] = ka;
        *(short8*)&wbuf[wvoff] = va;
    }

    // epilogue: direct from AGPR C-layout.  lane q = q0+ln31; regs 4g+j of
    // accO[dt] are d = dt*32 + 4*h2 + 8*g + j  -> contiguous float4 chunks.
    const float inv = 1.0f / accL[0];
    float* orow = out + ((size_t)(bb * SEQ + q0 + ln31) * NH + hh) * 64;
#pragma unroll
    for (int dt = 0; dt < 2; ++dt)
#pragma unroll
        for (int g = 0; g < 4; ++g) {
            float4 w;
            w.x = accO[dt][4 * g + 0] * inv;
            w.y = accO[dt][4 * g + 1] * inv;
            w.z = accO[dt][4 * g + 2] * inv;
            w.w = accO[dt][4 * g + 3] * inv;
            *(float4*)(orow + dt * 32 + 4 * h2 + 8 * g) = w;
        }
}

// ---------------------------------------------------------------------------
extern "C" void kernel_launch(void* const* d_in, const int* in_sizes, int n_in,
                              void* d_out, int out_size, void* d_ws, size_t ws_size,
                              hipStream_t stream) {
    const float* qf = (const float*)d_in[0];
    const float* kf = (const float*)d_in[1];
    const float* vf = (const float*)d_in[2];
    const float* Wq = (const float*)d_in[3];
    const float* bq = (const float*)d_in[4];
    const float* Wk = (const float*)d_in[5];
    const float* bk = (const float*)d_in[6];
    const float* Wv = (const float*)d_in[7];
    const float* bv = (const float*)d_in[8];

    char* ws = (char*)d_ws;
    unsigned short* Wt  = (unsigned short*)ws;               // 6 MB
    unsigned short* Qg  = (unsigned short*)(ws + 6291456);   // 16 MB [B,H,S,D]
    unsigned short* Kg  = Qg + 8388608;                      // 16 MB [B,H,S,D]
    unsigned short* Vt  = Kg + 8388608;                      // 16 MB [B,H,D,S]
    float* out = (float*)d_out;

    wt_kernel<<<dim3(16, 16, 3), 256, 0, stream>>>(Wq, Wk, Wv, Wt);
    proj_kernel<<<dim3(64, 4, 3), 512, 0, stream>>>(qf, kf, vf, Wt, bq, bk, bv, Qg, Kg, Vt);
    attn_kernel<<<dim3(8, 16, 4), 512, 0, stream>>>(Qg, Kg, Vt, out);
}